// Round 1
// baseline (98.041 us; speedup 1.0000x reference)
//
#include <hip/hip_runtime.h>
#include <math.h>

#define NFULL 4096
#define BATCH 8
#define LOG2E 1.44269504088896340736f

// m-dimension split for occupancy: 8 b * 16 n-tiles * GSPLIT m-groups waves
#define GSPLIT 16
#define NPT 4                    // n values per thread
#define MC (NFULL / GSPLIT)      // 256 m per wave

#if __has_builtin(__builtin_amdgcn_exp2f)
#define EXP2(x) __builtin_amdgcn_exp2f(x)
#else
#define EXP2(x) exp2f(x)
#endif

// Kernel A: per-point precompute.
// pm[b][n] = (K*x, K*y, K*z, smoothed * 2^(s' + 64))
//   where K = sqrt(4*log2e), s' = -2*log2e*||r||^2
//   smoothed = gs*(w0*p[n-1] + w1*p[n] + w2*p[n+1]) + bias   (zero-padded)
__global__ __launch_bounds__(256) void prep_kernel(
    const float* __restrict__ pred, const float* __restrict__ ray,
    const float* __restrict__ cw, const float* __restrict__ cb,
    const float* __restrict__ gs, float4* __restrict__ pm)
{
    int idx = blockIdx.x * 256 + threadIdx.x;      // 0..32767
    int b = idx >> 12, n = idx & (NFULL - 1);
    float g  = gs[0];
    float w0 = cw[0], w1 = cw[1], w2 = cw[2], bias = cb[0];
    const float* pd = pred + b * NFULL;
    float pm1 = (n > 0)         ? pd[n - 1] : 0.f;
    float p0  = pd[n];
    float pp1 = (n < NFULL - 1) ? pd[n + 1] : 0.f;
    float sm = g * (w0 * pm1 + w1 * p0 + w2 * pp1) + bias;

    const float* r = ray + (size_t)idx * 3;
    float x = r[0], y = r[1], z = r[2];
    float sq = x * x + y * y + z * z;
    float sp = -2.f * LOG2E * sq;                  // s'_m
    float shat = sm * EXP2(sp + 64.f);             // bounded: <= ~2e20

    const float K = 2.4022448f;                    // sqrt(4*log2e)
    pm[idx] = make_float4(K * x, K * y, K * z, shat);
}

// Kernel B: the N^2 pair loop.
// Each wave: one (b, n-tile of 256, m-chunk of MC). 4 n's per lane.
// acc_n = sum_m 2^(Cn + x^n.x^m + y^n.y^m + z^n.z^m) * shat_m
//   with Cn = s'_n - 64 recomputed from the scaled coords.
__global__ __launch_bounds__(256) void pairs_kernel(
    const float4* __restrict__ pm, float* __restrict__ partial)
{
    int tid  = threadIdx.x;
    int lane = tid & 63;
    int w    = blockIdx.x * 4 + (tid >> 6);        // wave id 0..2047
    int g  = w & (GSPLIT - 1);  w >>= 4;
    int nt = w & 15;            int b = w >> 4;

    const float4* P = pm + b * NFULL;
    int n0 = nt * 256 + lane;

    float4 a[NPT];
    float  Cn[NPT];
    float  acc[NPT];
#pragma unroll
    for (int k = 0; k < NPT; ++k) {
        a[k] = P[n0 + 64 * k];
        Cn[k] = -0.5f * (a[k].x * a[k].x + a[k].y * a[k].y + a[k].z * a[k].z) - 64.f;
        acc[k] = 0.f;
    }

    int m0 = g * MC;
#pragma unroll 4
    for (int m = m0; m < m0 + MC; ++m) {
        float4 q = P[m];                            // wave-uniform broadcast (L1 hit)
#pragma unroll
        for (int k = 0; k < NPT; ++k) {
            float t = fmaf(a[k].x, q.x, Cn[k]);
            t = fmaf(a[k].y, q.y, t);
            t = fmaf(a[k].z, q.z, t);
            acc[k] = fmaf(EXP2(t), q.w, acc[k]);
        }
    }

    float* outp = partial + (size_t)g * (BATCH * NFULL) + b * NFULL;
#pragma unroll
    for (int k = 0; k < NPT; ++k) outp[n0 + 64 * k] = acc[k];
}

// Kernel C: reduce the GSPLIT partials, clip, write output.
__global__ __launch_bounds__(256) void reduce_kernel(
    const float* __restrict__ partial, float* __restrict__ out)
{
    int idx = blockIdx.x * 256 + threadIdx.x;      // 0..32767
    float s = 0.f;
#pragma unroll
    for (int gg = 0; gg < GSPLIT; ++gg)
        s += partial[(size_t)gg * (BATCH * NFULL) + idx];
    out[idx] = fminf(fmaxf(s, 0.1f), 100.f);
}

extern "C" void kernel_launch(void* const* d_in, const int* in_sizes, int n_in,
                              void* d_out, int out_size, void* d_ws, size_t ws_size,
                              hipStream_t stream) {
    const float* pred = (const float*)d_in[0];   // (8,4096)
    const float* ray  = (const float*)d_in[1];   // (8,4096,3)
    const float* cw   = (const float*)d_in[2];   // (1,1,3)
    const float* cb   = (const float*)d_in[3];   // (1,)
    const float* gs   = (const float*)d_in[4];   // (1,)
    float* out = (float*)d_out;

    float4* pm      = (float4*)d_ws;                                   // 512 KB
    float*  partial = (float*)((char*)d_ws + (size_t)BATCH * NFULL * sizeof(float4)); // 2 MB

    prep_kernel<<<BATCH * NFULL / 256, 256, 0, stream>>>(pred, ray, cw, cb, gs, pm);
    pairs_kernel<<<(BATCH * 16 * GSPLIT) / 4, 256, 0, stream>>>(pm, partial);
    reduce_kernel<<<BATCH * NFULL / 256, 256, 0, stream>>>(partial, out);
}

// Round 2
// 87.936 us; speedup vs baseline: 1.1149x; 1.1149x over previous
//
#include <hip/hip_runtime.h>
#include <math.h>

#define NFULL 4096
#define BATCH 8
#define LOG2E 1.44269504088896340736f

// m-dimension split for occupancy: 8 b * 16 n-tiles * GSPLIT m-groups waves
#define GSPLIT 32
#define NPT 4                    // n values per thread
#define MC (NFULL / GSPLIT)      // 128 m per wave

typedef float v2f __attribute__((ext_vector_type(2)));

#if __has_builtin(__builtin_amdgcn_exp2f)
#define EXP2(x) __builtin_amdgcn_exp2f(x)
#else
#define EXP2(x) exp2f(x)
#endif

// Kernel A: per-point precompute.
// pm[b][n] = (K*x, K*y, K*z, smoothed * 2^(s' + 64))
//   where K = sqrt(4*log2e), s' = -2*log2e*||r||^2
//   smoothed = gs*(w0*p[n-1] + w1*p[n] + w2*p[n+1]) + bias   (zero-padded)
__global__ __launch_bounds__(256) void prep_kernel(
    const float* __restrict__ pred, const float* __restrict__ ray,
    const float* __restrict__ cw, const float* __restrict__ cb,
    const float* __restrict__ gs, float4* __restrict__ pm)
{
    int idx = blockIdx.x * 256 + threadIdx.x;      // 0..32767
    int b = idx >> 12, n = idx & (NFULL - 1);
    float g  = gs[0];
    float w0 = cw[0], w1 = cw[1], w2 = cw[2], bias = cb[0];
    const float* pd = pred + b * NFULL;
    float pm1 = (n > 0)         ? pd[n - 1] : 0.f;
    float p0  = pd[n];
    float pp1 = (n < NFULL - 1) ? pd[n + 1] : 0.f;
    float sm = g * (w0 * pm1 + w1 * p0 + w2 * pp1) + bias;

    const float* r = ray + (size_t)idx * 3;
    float x = r[0], y = r[1], z = r[2];
    float sq = x * x + y * y + z * z;
    float sp = -2.f * LOG2E * sq;                  // s'_m
    float shat = sm * EXP2(sp + 64.f);             // bounded, stays normal f32

    const float K = 2.4022448f;                    // sqrt(4*log2e)
    pm[idx] = make_float4(K * x, K * y, K * z, shat);
}

// Kernel B: the N^2 pair loop.
// Each wave: one (b, n-tile of 256, m-chunk of MC). 4 n's per lane,
// processed as two packed float2 pairs so dot/acc FMAs map to v_pk_fma_f32.
// acc_n = sum_m 2^(Cn + x^n.x^m + y^n.y^m + z^n.z^m) * shat_m
__global__ __launch_bounds__(256) void pairs_kernel(
    const float4* __restrict__ pm, float* __restrict__ partial)
{
    int tid  = threadIdx.x;
    int lane = tid & 63;
    int w    = blockIdx.x * 4 + (tid >> 6);        // wave id 0..4095
    int g  = w & (GSPLIT - 1);  w >>= 5;
    int nt = w & 15;            int b = w >> 4;

    const float4* P = pm + b * NFULL;
    int n0 = nt * 256 + lane;

    // packed per-lane n-state: pair p=0 holds (k=0,k=1), p=1 holds (k=2,k=3)
    v2f ax[2], ay[2], az[2], Cn[2], acc[2];
#pragma unroll
    for (int p = 0; p < 2; ++p) {
        float4 a0 = P[n0 + 64 * (2 * p)];
        float4 a1 = P[n0 + 64 * (2 * p + 1)];
        ax[p] = (v2f){a0.x, a1.x};
        ay[p] = (v2f){a0.y, a1.y};
        az[p] = (v2f){a0.z, a1.z};
        v2f sq = __builtin_elementwise_fma(ax[p], ax[p],
                 __builtin_elementwise_fma(ay[p], ay[p], az[p] * az[p]));
        Cn[p] = -0.5f * sq - 64.f;
        acc[p] = (v2f){0.f, 0.f};
    }

    int m0 = g * MC;
#pragma unroll 8
    for (int m = m0; m < m0 + MC; ++m) {
        float4 q = P[m];                            // wave-uniform broadcast (L1 hit)
        v2f qx = (v2f){q.x, q.x}, qy = (v2f){q.y, q.y},
            qz = (v2f){q.z, q.z}, qw = (v2f){q.w, q.w};
#pragma unroll
        for (int p = 0; p < 2; ++p) {
            v2f t = __builtin_elementwise_fma(ax[p], qx, Cn[p]);
            t = __builtin_elementwise_fma(ay[p], qy, t);
            t = __builtin_elementwise_fma(az[p], qz, t);
            v2f e = (v2f){EXP2(t.x), EXP2(t.y)};
            acc[p] = __builtin_elementwise_fma(e, qw, acc[p]);
        }
    }

    float* outp = partial + (size_t)g * (BATCH * NFULL) + b * NFULL;
#pragma unroll
    for (int p = 0; p < 2; ++p) {
        outp[n0 + 64 * (2 * p)]     = acc[p].x;
        outp[n0 + 64 * (2 * p + 1)] = acc[p].y;
    }
}

// Kernel C: reduce the GSPLIT partials, clip, write output.
__global__ __launch_bounds__(256) void reduce_kernel(
    const float4* __restrict__ partial, float4* __restrict__ out)
{
    int idx = blockIdx.x * 256 + threadIdx.x;      // 0..8191 (float4 granules)
    float4 s = make_float4(0.f, 0.f, 0.f, 0.f);
#pragma unroll
    for (int gg = 0; gg < GSPLIT; ++gg) {
        float4 v = partial[(size_t)gg * (BATCH * NFULL / 4) + idx];
        s.x += v.x; s.y += v.y; s.z += v.z; s.w += v.w;
    }
    float4 r;
    r.x = fminf(fmaxf(s.x, 0.1f), 100.f);
    r.y = fminf(fmaxf(s.y, 0.1f), 100.f);
    r.z = fminf(fmaxf(s.z, 0.1f), 100.f);
    r.w = fminf(fmaxf(s.w, 0.1f), 100.f);
    out[idx] = r;
}

extern "C" void kernel_launch(void* const* d_in, const int* in_sizes, int n_in,
                              void* d_out, int out_size, void* d_ws, size_t ws_size,
                              hipStream_t stream) {
    const float* pred = (const float*)d_in[0];   // (8,4096)
    const float* ray  = (const float*)d_in[1];   // (8,4096,3)
    const float* cw   = (const float*)d_in[2];   // (1,1,3)
    const float* cb   = (const float*)d_in[3];   // (1,)
    const float* gs   = (const float*)d_in[4];   // (1,)

    float4* pm      = (float4*)d_ws;                                   // 512 KB
    float*  partial = (float*)((char*)d_ws + (size_t)BATCH * NFULL * sizeof(float4)); // 4 MB

    prep_kernel<<<BATCH * NFULL / 256, 256, 0, stream>>>(pred, ray, cw, cb, gs, pm);
    pairs_kernel<<<(BATCH * 16 * GSPLIT) / 4, 256, 0, stream>>>(pm, partial);
    reduce_kernel<<<BATCH * NFULL / 1024, 256, 0, stream>>>(
        (const float4*)partial, (float4*)d_out);
}

// Round 3
// 87.292 us; speedup vs baseline: 1.1231x; 1.0074x over previous
//
#include <hip/hip_runtime.h>
#include <math.h>

#define NFULL 4096
#define BATCH 8
#define LOG2E 1.44269504088896340736f

// m-dimension split: grid = BATCH * 4 n-tiles * GSPLIT m-groups (blocks)
#define GSPLIT 64
#define MC (NFULL / GSPLIT)      // 64 m per block
#define NPT 4                    // n values per thread

typedef float v2f __attribute__((ext_vector_type(2)));

#if __has_builtin(__builtin_amdgcn_exp2f)
#define EXP2(x) __builtin_amdgcn_exp2f(x)
#else
#define EXP2(x) exp2f(x)
#endif

// Kernel A: per-point precompute.
// pm[b][n] = (K*x, K*y, K*z, smoothed * 2^(s' + 64))
//   where K = sqrt(4*log2e), s' = -2*log2e*||r||^2
//   smoothed = gs*(w0*p[n-1] + w1*p[n] + w2*p[n+1]) + bias   (zero-padded)
__global__ __launch_bounds__(256) void prep_kernel(
    const float* __restrict__ pred, const float* __restrict__ ray,
    const float* __restrict__ cw, const float* __restrict__ cb,
    const float* __restrict__ gs, float4* __restrict__ pm)
{
    int idx = blockIdx.x * 256 + threadIdx.x;      // 0..32767
    int b = idx >> 12, n = idx & (NFULL - 1);
    float g  = gs[0];
    float w0 = cw[0], w1 = cw[1], w2 = cw[2], bias = cb[0];
    const float* pd = pred + b * NFULL;
    float pm1 = (n > 0)         ? pd[n - 1] : 0.f;
    float p0  = pd[n];
    float pp1 = (n < NFULL - 1) ? pd[n + 1] : 0.f;
    float sm = g * (w0 * pm1 + w1 * p0 + w2 * pp1) + bias;

    const float* r = ray + (size_t)idx * 3;
    float x = r[0], y = r[1], z = r[2];
    float sq = x * x + y * y + z * z;
    float sp = -2.f * LOG2E * sq;                  // s'_m
    float shat = sm * EXP2(sp + 64.f);             // bounded, stays normal f32

    const float K = 2.4022448f;                    // sqrt(4*log2e)
    pm[idx] = make_float4(K * x, K * y, K * z, shat);
}

// Kernel B: the N^2 pair loop.
// Block = (b, n-tile of 1024, m-chunk of MC). All 4 waves in a block share
// the same m-range -> P[m] address is workgroup-uniform (blockIdx-derived
// only) -> scalar s_load_dwordx4, q components become SGPR broadcast FMA
// operands (zero VALU issue cost for the load).
// Each lane: 4 n's as two packed float2 pairs (v_pk_fma_f32).
// acc_n = sum_m 2^(Cn + x^n.x^m + y^n.y^m + z^n.z^m) * shat_m
__global__ __launch_bounds__(256, 8) void pairs_kernel(
    const float4* __restrict__ pm, float* __restrict__ partial)
{
    int tid  = threadIdx.x;
    int lane = tid & 63;
    int wv   = tid >> 6;
    int e  = blockIdx.x;                 // 0..2047
    int g  = e & (GSPLIT - 1);           // m-group   (block-uniform)
    int w2 = e >> 6;
    int nt = w2 & 3;                     // n-tile of 1024
    int b  = w2 >> 2;                    // batch

    const float4* P = pm + b * NFULL;
    int n0 = nt * 1024 + wv * 256 + lane;

    // packed per-lane n-state: pair p=0 holds (k=0,k=1), p=1 holds (k=2,k=3)
    v2f ax[2], ay[2], az[2], Cn[2], acc[2];
#pragma unroll
    for (int p = 0; p < 2; ++p) {
        float4 a0 = P[n0 + 64 * (2 * p)];
        float4 a1 = P[n0 + 64 * (2 * p + 1)];
        ax[p] = (v2f){a0.x, a1.x};
        ay[p] = (v2f){a0.y, a1.y};
        az[p] = (v2f){a0.z, a1.z};
        v2f sq = __builtin_elementwise_fma(ax[p], ax[p],
                 __builtin_elementwise_fma(ay[p], ay[p], az[p] * az[p]));
        Cn[p] = -0.5f * sq - 64.f;
        acc[p] = (v2f){0.f, 0.f};
    }

    int m0 = g * MC;                     // block-uniform
#pragma unroll 8
    for (int m = m0; m < m0 + MC; ++m) {
        float4 q = P[m];                 // uniform -> s_load_dwordx4
#pragma unroll
        for (int p = 0; p < 2; ++p) {
            v2f t = __builtin_elementwise_fma(ax[p], (v2f){q.x, q.x}, Cn[p]);
            t = __builtin_elementwise_fma(ay[p], (v2f){q.y, q.y}, t);
            t = __builtin_elementwise_fma(az[p], (v2f){q.z, q.z}, t);
            v2f ee = (v2f){EXP2(t.x), EXP2(t.y)};
            acc[p] = __builtin_elementwise_fma(ee, (v2f){q.w, q.w}, acc[p]);
        }
    }

    float* outp = partial + (size_t)g * (BATCH * NFULL) + b * NFULL;
#pragma unroll
    for (int p = 0; p < 2; ++p) {
        outp[n0 + 64 * (2 * p)]     = acc[p].x;
        outp[n0 + 64 * (2 * p + 1)] = acc[p].y;
    }
}

// Kernel C: reduce the GSPLIT partials, clip, write output.
__global__ __launch_bounds__(256) void reduce_kernel(
    const float4* __restrict__ partial, float4* __restrict__ out)
{
    int idx = blockIdx.x * 256 + threadIdx.x;      // 0..8191 (float4 granules)
    float4 s = make_float4(0.f, 0.f, 0.f, 0.f);
#pragma unroll
    for (int gg = 0; gg < GSPLIT; ++gg) {
        float4 v = partial[(size_t)gg * (BATCH * NFULL / 4) + idx];
        s.x += v.x; s.y += v.y; s.z += v.z; s.w += v.w;
    }
    float4 r;
    r.x = fminf(fmaxf(s.x, 0.1f), 100.f);
    r.y = fminf(fmaxf(s.y, 0.1f), 100.f);
    r.z = fminf(fmaxf(s.z, 0.1f), 100.f);
    r.w = fminf(fmaxf(s.w, 0.1f), 100.f);
    out[idx] = r;
}

extern "C" void kernel_launch(void* const* d_in, const int* in_sizes, int n_in,
                              void* d_out, int out_size, void* d_ws, size_t ws_size,
                              hipStream_t stream) {
    const float* pred = (const float*)d_in[0];   // (8,4096)
    const float* ray  = (const float*)d_in[1];   // (8,4096,3)
    const float* cw   = (const float*)d_in[2];   // (1,1,3)
    const float* cb   = (const float*)d_in[3];   // (1,)
    const float* gs   = (const float*)d_in[4];   // (1,)

    float4* pm      = (float4*)d_ws;                                   // 512 KB
    float*  partial = (float*)((char*)d_ws + (size_t)BATCH * NFULL * sizeof(float4)); // 8 MB

    prep_kernel<<<BATCH * NFULL / 256, 256, 0, stream>>>(pred, ray, cw, cb, gs, pm);
    pairs_kernel<<<BATCH * 4 * GSPLIT, 256, 0, stream>>>(pm, partial);
    reduce_kernel<<<BATCH * NFULL / 1024, 256, 0, stream>>>(
        (const float4*)partial, (float4*)d_out);
}

// Round 4
// 86.666 us; speedup vs baseline: 1.1312x; 1.0072x over previous
//
#include <hip/hip_runtime.h>
#include <math.h>

#define NFULL 4096
#define BATCH 8
#define LOG2E 1.44269504088896340736f

// m-dimension split: grid = BATCH * 4 n-tiles * GSPLIT m-groups (blocks)
#define GSPLIT 64
#define MC (NFULL / GSPLIT)      // 64 m per block

typedef float v2f __attribute__((ext_vector_type(2)));

#if __has_builtin(__builtin_amdgcn_exp2f)
#define EXP2(x) __builtin_amdgcn_exp2f(x)
#else
#define EXP2(x) exp2f(x)
#endif

// Fused kernel: per-block m-prep into LDS + N^2 pair loop.
// Block = (b, n-tile of 1024, m-chunk of MC=64).
//   m-prep (threads 0..63): Q[j] = (K*x, K*y, K*z, smoothed * 2^(s'+64))
//     where K = sqrt(4*log2e), s' = -2*log2e*||r||^2,
//     smoothed = gs*(w0*p[m-1]+w1*p[m]+w2*p[m+1]) + bias (zero-padded)
//   n-prep (per thread, 4 n's): scaled coords + Cn = -2*log2e*||r_n||^2 - 64
//   main loop: acc_n += 2^(Cn + a_n . q_m) * shat_m   (q from LDS broadcast)
// Exponent bound: 2.885*max||r||^2 - 64 stays well inside f32 range.
__global__ __launch_bounds__(256, 8) void pairs_kernel(
    const float* __restrict__ pred, const float* __restrict__ ray,
    const float* __restrict__ cw, const float* __restrict__ cb,
    const float* __restrict__ gs, float* __restrict__ partial)
{
    __shared__ float4 Q[MC];             // 1 KB

    int tid  = threadIdx.x;
    int lane = tid & 63;
    int wv   = tid >> 6;
    int e  = blockIdx.x;                 // 0..2047
    int g  = e & (GSPLIT - 1);           // m-group   (block-uniform)
    int w2 = e >> 6;
    int nt = w2 & 3;                     // n-tile of 1024
    int b  = w2 >> 2;                    // batch

    const float K = 2.4022448f;          // sqrt(4*log2e)

    // ---- m-prep into LDS (threads 0..MC-1) ----
    if (tid < MC) {
        int m = g * MC + tid;
        const float* pd = pred + b * NFULL;
        float pm1 = (m > 0)         ? pd[m - 1] : 0.f;
        float p0  = pd[m];
        float pp1 = (m < NFULL - 1) ? pd[m + 1] : 0.f;
        float sm = gs[0] * (cw[0] * pm1 + cw[1] * p0 + cw[2] * pp1) + cb[0];

        const float* r = ray + (size_t)(b * NFULL + m) * 3;
        float x = r[0], y = r[1], z = r[2];
        float sp = -2.f * LOG2E * (x * x + y * y + z * z);
        Q[tid] = make_float4(K * x, K * y, K * z, sm * EXP2(sp + 64.f));
    }

    // ---- n-prep (4 n's per thread, packed into two float2 pairs) ----
    int n0 = nt * 1024 + wv * 256 + lane;
    v2f ax[2], ay[2], az[2], Cn[2], acc[2];
#pragma unroll
    for (int p = 0; p < 2; ++p) {
        const float* r0 = ray + (size_t)(b * NFULL + n0 + 64 * (2 * p)) * 3;
        const float* r1 = ray + (size_t)(b * NFULL + n0 + 64 * (2 * p + 1)) * 3;
        ax[p] = (v2f){K * r0[0], K * r1[0]};
        ay[p] = (v2f){K * r0[1], K * r1[1]};
        az[p] = (v2f){K * r0[2], K * r1[2]};
        v2f sq = __builtin_elementwise_fma(ax[p], ax[p],
                 __builtin_elementwise_fma(ay[p], ay[p], az[p] * az[p]));
        Cn[p] = -0.5f * sq - 64.f;
        acc[p] = (v2f){0.f, 0.f};
    }
    __syncthreads();

    // ---- main loop over the block's m-chunk ----
#pragma unroll 8
    for (int m = 0; m < MC; ++m) {
        float4 q = Q[m];                 // uniform addr -> LDS broadcast
#pragma unroll
        for (int p = 0; p < 2; ++p) {
            v2f t = __builtin_elementwise_fma(ax[p], (v2f){q.x, q.x}, Cn[p]);
            t = __builtin_elementwise_fma(ay[p], (v2f){q.y, q.y}, t);
            t = __builtin_elementwise_fma(az[p], (v2f){q.z, q.z}, t);
            v2f ee = (v2f){EXP2(t.x), EXP2(t.y)};
            acc[p] = __builtin_elementwise_fma(ee, (v2f){q.w, q.w}, acc[p]);
        }
    }

    float* outp = partial + (size_t)g * (BATCH * NFULL) + b * NFULL;
#pragma unroll
    for (int p = 0; p < 2; ++p) {
        outp[n0 + 64 * (2 * p)]     = acc[p].x;
        outp[n0 + 64 * (2 * p + 1)] = acc[p].y;
    }
}

// Reduce the GSPLIT partials, clip, write output.
__global__ __launch_bounds__(256) void reduce_kernel(
    const float4* __restrict__ partial, float4* __restrict__ out)
{
    int idx = blockIdx.x * 256 + threadIdx.x;      // 0..8191 (float4 granules)
    float4 s = make_float4(0.f, 0.f, 0.f, 0.f);
#pragma unroll
    for (int gg = 0; gg < GSPLIT; ++gg) {
        float4 v = partial[(size_t)gg * (BATCH * NFULL / 4) + idx];
        s.x += v.x; s.y += v.y; s.z += v.z; s.w += v.w;
    }
    float4 r;
    r.x = fminf(fmaxf(s.x, 0.1f), 100.f);
    r.y = fminf(fmaxf(s.y, 0.1f), 100.f);
    r.z = fminf(fmaxf(s.z, 0.1f), 100.f);
    r.w = fminf(fmaxf(s.w, 0.1f), 100.f);
    out[idx] = r;
}

extern "C" void kernel_launch(void* const* d_in, const int* in_sizes, int n_in,
                              void* d_out, int out_size, void* d_ws, size_t ws_size,
                              hipStream_t stream) {
    const float* pred = (const float*)d_in[0];   // (8,4096)
    const float* ray  = (const float*)d_in[1];   // (8,4096,3)
    const float* cw   = (const float*)d_in[2];   // (1,1,3)
    const float* cb   = (const float*)d_in[3];   // (1,)
    const float* gs   = (const float*)d_in[4];   // (1,)

    float* partial = (float*)d_ws;               // GSPLIT * 8 * 4096 * 4B = 8 MB

    pairs_kernel<<<BATCH * 4 * GSPLIT, 256, 0, stream>>>(pred, ray, cw, cb, gs, partial);
    reduce_kernel<<<BATCH * NFULL / 1024, 256, 0, stream>>>(
        (const float4*)partial, (float4*)d_out);
}